// Round 3
// baseline (973.227 us; speedup 1.0000x reference)
//
#include <hip/hip_runtime.h>
#include <math.h>

// Problem dims (fixed by the reference)
#define B_ 8
#define L_ 8192
#define H_ 128
#define N_ 32
#define C_ 128   // chunks along L (= threads per k_s4d block)
#define T_ 64    // chunk length (C_*T_ == L_)

// ws layout: Wt float[H_*256] @ 0 (128 KB); gy float[B_*H_*L_] @ 131072 (32 MB)
// gy per (b,h) is stored at index t*C_+c (fixed permutation of l; k_mix is
// pointwise-over-l + mean-pool, so any fixed permutation is fine)

__device__ __forceinline__ float gelu_tanh(float y) {
    float t = 0.7978845608028654f * fmaf(0.044715f, y * y * y, y);
    float e = __expf(2.f * t);
    float th = 1.f - __fdividef(2.f, e + 1.f);
    return 0.5f * y * (1.f + th);
}

// ---------------------------------------------------------------------------
// k_setup: out_w transpose (Wt[h][g] = out_w[g][h]) + out init
// ---------------------------------------------------------------------------
__global__ __launch_bounds__(256) void k_setup(
    const float* __restrict__ out_w, const float* __restrict__ dec_b,
    float* __restrict__ out, float* __restrict__ Wt)
{
    int blk = blockIdx.x, tid = threadIdx.x;
    if (blk < 128) {
        int idx = blk * 256 + tid;            // 0..32767
        int h = idx >> 8, g = idx & 255;
        Wt[idx] = out_w[g * H_ + h];          // write coalesced, read L2-hit
    } else {
        if (tid < B_) out[tid] = dec_b[0];
    }
}

// ---------------------------------------------------------------------------
// k_s4d: fused encoder + chunked S4D scan + skip + GELU. Block = (b,h),
// 128 threads (2 waves), thread = chunk c.
//  P1: chunk Horner sums via w^2 double-steps (zero-init states).
//  P2: in-wave shuffle scan (6 steps) + one LDS step (s=64) + shift-by-1.
//  P3: replay chunk with incoming state, project, skip+GELU, store gy.
// ---------------------------------------------------------------------------
__global__ __launch_bounds__(128, 4) void k_s4d(
    const float* __restrict__ x, const float* __restrict__ enc_w,
    const float* __restrict__ enc_b, const float* __restrict__ log_dt,
    const float* __restrict__ log_A_real, const float* __restrict__ A_imag,
    const float* __restrict__ C_re, const float* __restrict__ C_im,
    const float* __restrict__ Dp, float* __restrict__ gy)
{
    const int bh = blockIdx.x;
    const int b = bh >> 7, h = bh & (H_ - 1);
    const int c = threadIdx.x;
    const int lane = c & 63, wv = c >> 6;

    __shared__ float4 cw4[N_];        // (wr, wi, coef_r, coef_i)
    __shared__ float4 pw[N_];         // (w2r, w2i, wr, wi)
    __shared__ float2 wTpow[7][N_];   // wT^(2^k), k=0..6
    __shared__ float2 Sx[N_][64];     // wave-0 inclusive scans (16 KB)

    if (c < N_) {
        int idx = h * N_ + c;
        float dt = expf(log_dt[h]);
        float Ar = -expf(log_A_real[idx]);
        float Ai = A_imag[idx];
        float ar = dt * Ar, ai = dt * Ai;
        float er = expf(ar);
        float wr = er * cosf(ai), wi = er * sinf(ai);
        float numr = wr - 1.f, numi = wi;
        float inv = 1.f / (Ar * Ar + Ai * Ai);
        float qr = (numr * Ar + numi * Ai) * inv;
        float qi = (numi * Ar - numr * Ai) * inv;
        cw4[c] = make_float4(wr, wi, C_re[idx] * qr - C_im[idx] * qi,
                                     C_re[idx] * qi + C_im[idx] * qr);
        pw[c] = make_float4(wr * wr - wi * wi, 2.f * wr * wi, wr, wi);
        float erT = expf(ar * (float)T_);
        float pr = erT * cosf(ai * (float)T_), pi = erT * sinf(ai * (float)T_);
#pragma unroll
        for (int k = 0; k < 7; ++k) {
            wTpow[k][c] = make_float2(pr, pi);
            float nr = pr * pr - pi * pi;
            pi = 2.f * pr * pi; pr = nr;
        }
    }
    __syncthreads();

    const float2* xb = (const float2*)x + (size_t)b * L_ + c * T_;
    const float ew0 = enc_w[h], ew1 = enc_w[H_ + h], eb = enc_b[h];

    // ---- Phase 1: E[c] via w^2 double-steps, zero-init ----
    float zr[N_], zi[N_];
#pragma unroll
    for (int n = 0; n < N_; ++n) { zr[n] = 0.f; zi[n] = 0.f; }
    {
        const float4* xq = (const float4*)xb;   // each float4 = 2 timesteps
        float4 xv = xq[0];
#pragma unroll 2
        for (int t2 = 0; t2 < T_ / 2; ++t2) {
            float ua = fmaf(xv.x, ew0, fmaf(xv.y, ew1, eb));
            float ub = fmaf(xv.z, ew0, fmaf(xv.w, ew1, eb));
            if (t2 < T_ / 2 - 1) xv = xq[t2 + 1];
#pragma unroll
            for (int n = 0; n < N_; ++n) {
                float4 q = pw[n];
                float mr = fmaf(q.z, ua, ub);
                float mi = q.w * ua;
                float nr = fmaf(q.x, zr[n], fmaf(-q.y, zi[n], mr));
                zi[n] = fmaf(q.x, zi[n], fmaf(q.y, zr[n], mi));
                zr[n] = nr;
            }
        }
    }

    // ---- Phase 2: scan over chunks ----
    // in-wave inclusive scan, 6 shuffle steps
#pragma unroll
    for (int k = 0; k < 6; ++k) {
        int s = 1 << k;
        float mask = (lane >= s) ? 1.f : 0.f;
#pragma unroll
        for (int n = 0; n < N_; ++n) {
            float2 q = wTpow[k][n];
            float vr = __shfl_up(zr[n], s, 64);
            float vi = __shfl_up(zi[n], s, 64);
            float adr = fmaf(q.x, vr, -(q.y * vi));
            float adi = fmaf(q.x, vi, q.y * vr);
            zr[n] = fmaf(mask, adr, zr[n]);
            zi[n] = fmaf(mask, adi, zi[n]);
        }
    }
    // wave 0 publishes its inclusive scan
    if (wv == 0) {
#pragma unroll
        for (int n = 0; n < N_; ++n) Sx[n][lane] = make_float2(zr[n], zi[n]);
    }
    __syncthreads();
    // wave 1: s=64 step with uniform weight wT^64
    if (wv == 1) {
#pragma unroll
        for (int n = 0; n < N_; ++n) {
            float2 q = wTpow[6][n];
            float2 v = Sx[n][lane];
            zr[n] = fmaf(q.x, v.x, fmaf(-q.y, v.y, zr[n]));
            zi[n] = fmaf(q.x, v.y, fmaf(q.y, v.x, zi[n]));
        }
    }
    // shift by one chunk: S_in[c] = I[c-1]
    {
        bool l0 = (lane == 0);
#pragma unroll
        for (int n = 0; n < N_; ++n) {
            float2 bv = Sx[n][63];           // valid for both waves
            float br = (wv == 1) ? bv.x : 0.f;
            float bi = (wv == 1) ? bv.y : 0.f;
            float tr = __shfl_up(zr[n], 1, 64);
            float ti = __shfl_up(zi[n], 1, 64);
            zr[n] = l0 ? br : tr;
            zi[n] = l0 ? bi : ti;
        }
    }

    // ---- Phase 3: replay chunk with incoming state; skip+GELU; store ----
    const float Dh = Dp[h];
    float* gyp = gy + (size_t)(b * H_ + h) * L_ + c;
    {
        float2 xv[4];
#pragma unroll
        for (int j = 0; j < 4; ++j) xv[j] = xb[j];
#pragma unroll 1
        for (int t4 = 0; t4 < T_ / 4; ++t4) {
            float u[4], p[4];
#pragma unroll
            for (int j = 0; j < 4; ++j) {
                u[j] = fmaf(xv[j].x, ew0, fmaf(xv[j].y, ew1, eb));
                p[j] = 0.f;
            }
            if (t4 < T_ / 4 - 1) {
#pragma unroll
                for (int j = 0; j < 4; ++j) xv[j] = xb[(t4 + 1) * 4 + j];
            }
#pragma unroll
            for (int n = 0; n < N_; ++n) {
                float4 q = cw4[n];
                float ar_ = zr[n], ai_ = zi[n];
#pragma unroll
                for (int j = 0; j < 4; ++j) {
                    float nr = fmaf(q.x, ar_, fmaf(-q.y, ai_, u[j]));
                    ai_ = fmaf(q.x, ai_, q.y * ar_);
                    ar_ = nr;
                    p[j] = fmaf(q.z, ar_, fmaf(-q.w, ai_, p[j]));
                }
                zr[n] = ar_; zi[n] = ai_;
            }
#pragma unroll
            for (int j = 0; j < 4; ++j) {
                float y = fmaf(Dh, u[j], 2.f * p[j]);
                gyp[(size_t)(t4 * 4 + j) * C_] = gelu_tanh(y);
            }
        }
    }
}

// ---------------------------------------------------------------------------
// k_mix: pointwise GLU mix + pooled decode. 16-deep gy prefetch per h-half.
// ---------------------------------------------------------------------------
__global__ __launch_bounds__(256) void k_mix(
    const float* __restrict__ Wt, const float* __restrict__ gy,
    const float* __restrict__ out_b, const float* __restrict__ dec_w,
    float* __restrict__ out)
{
    __shared__ float Wl[32][256];
    __shared__ float red[4];
    int blk = blockIdx.x;
    int b = blk >> 7, lt = blk & 127;
    int l0 = lt * 64;
    int tid = threadIdx.x;
    int wq = tid >> 6, lane = tid & 63;
    int g0 = wq * 32;

    float aa[32], ag[32];
#pragma unroll
    for (int j = 0; j < 32; ++j) { aa[j] = 0.f; ag[j] = 0.f; }

    for (int hc = 0; hc < 4; ++hc) {
        __syncthreads();
        const float4* src = (const float4*)(Wt + hc * 32 * 256);
        float4* dst = (float4*)(&Wl[0][0]);
#pragma unroll
        for (int r = 0; r < 8; ++r) dst[r * 256 + tid] = src[r * 256 + tid];
        __syncthreads();
        const float* gp = gy + (size_t)(b * H_ + hc * 32) * L_ + l0 + lane;
#pragma unroll
        for (int half = 0; half < 2; ++half) {
            float v[16];
#pragma unroll
            for (int j = 0; j < 16; ++j)
                v[j] = gp[(size_t)(half * 16 + j) * L_];   // 16 loads in flight
#pragma unroll
            for (int j = 0; j < 16; ++j) {
                int hh = half * 16 + j;
#pragma unroll
                for (int j4 = 0; j4 < 8; ++j4) {
                    float4 wa = *(const float4*)&Wl[hh][g0 + j4 * 4];
                    float4 wg = *(const float4*)&Wl[hh][128 + g0 + j4 * 4];
                    aa[j4 * 4 + 0] = fmaf(wa.x, v[j], aa[j4 * 4 + 0]);
                    aa[j4 * 4 + 1] = fmaf(wa.y, v[j], aa[j4 * 4 + 1]);
                    aa[j4 * 4 + 2] = fmaf(wa.z, v[j], aa[j4 * 4 + 2]);
                    aa[j4 * 4 + 3] = fmaf(wa.w, v[j], aa[j4 * 4 + 3]);
                    ag[j4 * 4 + 0] = fmaf(wg.x, v[j], ag[j4 * 4 + 0]);
                    ag[j4 * 4 + 1] = fmaf(wg.y, v[j], ag[j4 * 4 + 1]);
                    ag[j4 * 4 + 2] = fmaf(wg.z, v[j], ag[j4 * 4 + 2]);
                    ag[j4 * 4 + 3] = fmaf(wg.w, v[j], ag[j4 * 4 + 3]);
                }
            }
        }
    }
    float s = 0.f;
#pragma unroll
    for (int j = 0; j < 32; ++j) {
        int g = g0 + j;
        float za = aa[j] + out_b[g];
        float zg = ag[j] + out_b[128 + g];
        float sig = __fdividef(1.f, 1.f + __expf(-zg));
        s = fmaf(dec_w[g], za * sig, s);
    }
#pragma unroll
    for (int off = 32; off; off >>= 1) s += __shfl_down(s, off, 64);
    if (lane == 0) red[wq] = s;
    __syncthreads();
    if (tid == 0) {
        float tot = (red[0] + red[1] + red[2] + red[3]) * (1.0f / (float)L_);
        atomicAdd(out + b, tot);
    }
}

// ---------------------------------------------------------------------------
extern "C" void kernel_launch(void* const* d_in, const int* in_sizes, int n_in,
                              void* d_out, int out_size, void* d_ws, size_t ws_size,
                              hipStream_t stream)
{
    const float* x         = (const float*)d_in[0];
    const float* enc_w     = (const float*)d_in[1];
    const float* enc_b     = (const float*)d_in[2];
    const float* log_dt    = (const float*)d_in[3];
    const float* log_A_real= (const float*)d_in[4];
    const float* A_imag    = (const float*)d_in[5];
    const float* C_re      = (const float*)d_in[6];
    const float* C_im      = (const float*)d_in[7];
    const float* Dp        = (const float*)d_in[8];
    const float* out_w     = (const float*)d_in[9];
    const float* out_b     = (const float*)d_in[10];
    const float* dec_w     = (const float*)d_in[11];
    const float* dec_b     = (const float*)d_in[12];
    float* out = (float*)d_out;

    char* ws = (char*)d_ws;
    float* Wt = (float*)(ws);
    float* gy = (float*)(ws + 131072);

    k_setup<<<129, 256, 0, stream>>>(out_w, dec_b, out, Wt);
    k_s4d<<<B_ * H_, C_, 0, stream>>>(x, enc_w, enc_b, log_dt, log_A_real,
                                      A_imag, C_re, C_im, Dp, gy);
    k_mix<<<B_ * 128, 256, 0, stream>>>(Wt, gy, out_b, dec_w, out);
}

// Round 4
// 218.262 us; speedup vs baseline: 4.4590x; 4.4590x over previous
//
#include <hip/hip_runtime.h>
#include <math.h>

// Problem dims (fixed by the reference)
#define B_ 8
#define L_ 8192
#define H_ 128
#define N_ 32
#define C_ 128   // chunks along L (= threads per k_s4d block)
#define T_ 64    // chunk length (C_*T_ == L_)

// ws layout: Wt float[H_*256] @ 0 (128 KB); gy float[B_*H_*L_] @ 131072 (32 MB)
// gy per (b,h) stored at index t*C_+c (fixed permutation of l; k_mix is
// pointwise-over-l + mean-pool, so any fixed permutation is fine)

__device__ __forceinline__ float gelu_tanh(float y) {
    float t = 0.7978845608028654f * fmaf(0.044715f, y * y * y, y);
    float e = __expf(2.f * t);
    float th = 1.f - __fdividef(2.f, e + 1.f);
    return 0.5f * y * (1.f + th);
}

// ---------------------------------------------------------------------------
// k_setup: out_w transpose (Wt[h][g] = out_w[g][h]) + out init
// ---------------------------------------------------------------------------
__global__ __launch_bounds__(256) void k_setup(
    const float* __restrict__ out_w, const float* __restrict__ dec_b,
    float* __restrict__ out, float* __restrict__ Wt)
{
    int blk = blockIdx.x, tid = threadIdx.x;
    if (blk < 128) {
        int idx = blk * 256 + tid;            // 0..32767
        int h = idx >> 8, g = idx & 255;
        Wt[idx] = out_w[g * H_ + h];
    } else {
        if (tid < B_) out[tid] = dec_b[0];
    }
}

// ---------------------------------------------------------------------------
// k_s4d: fused encoder + chunked S4D scan + skip + GELU. Block = (b,h),
// 128 threads (2 waves), thread = chunk c. NO min-wave launch bound: the 64
// state VGPRs + tiles need ~150 regs; forcing fewer spills to scratch (R3:
// 3.7 GB of spill traffic, 7x regression).
//  P1: chunk Horner sums via w^2 double-steps; n tiled by 4 (q in VGPRs),
//      16-timestep u tile in regs -> ds_read pressure cut 8x.
//  P2: in-wave shuffle scan (6 steps) + one LDS step (s=64) + shift-by-1.
//  P3: replay with incoming state, n tiled by 4; skip+GELU; store gy.
// ---------------------------------------------------------------------------
__global__ __launch_bounds__(128) void k_s4d(
    const float* __restrict__ x, const float* __restrict__ enc_w,
    const float* __restrict__ enc_b, const float* __restrict__ log_dt,
    const float* __restrict__ log_A_real, const float* __restrict__ A_imag,
    const float* __restrict__ C_re, const float* __restrict__ C_im,
    const float* __restrict__ Dp, float* __restrict__ gy)
{
    const int bh = blockIdx.x;
    const int b = bh >> 7, h = bh & (H_ - 1);
    const int c = threadIdx.x;
    const int lane = c & 63, wv = c >> 6;

    __shared__ float4 cw4[N_];        // (wr, wi, coef_r, coef_i)
    __shared__ float4 pw[N_];         // (w2r, w2i, wr, wi)
    __shared__ float2 wTpow[7][N_];   // wT^(2^k), k=0..6
    __shared__ float2 Sx[N_][64];     // wave-0 inclusive scans (16 KB)

    if (c < N_) {
        int idx = h * N_ + c;
        float dt = expf(log_dt[h]);
        float Ar = -expf(log_A_real[idx]);
        float Ai = A_imag[idx];
        float ar = dt * Ar, ai = dt * Ai;
        float er = expf(ar);
        float wr = er * cosf(ai), wi = er * sinf(ai);
        float numr = wr - 1.f, numi = wi;
        float inv = 1.f / (Ar * Ar + Ai * Ai);
        float qr = (numr * Ar + numi * Ai) * inv;
        float qi = (numi * Ar - numr * Ai) * inv;
        cw4[c] = make_float4(wr, wi, C_re[idx] * qr - C_im[idx] * qi,
                                     C_re[idx] * qi + C_im[idx] * qr);
        pw[c] = make_float4(wr * wr - wi * wi, 2.f * wr * wi, wr, wi);
        float erT = expf(ar * (float)T_);
        float pr = erT * cosf(ai * (float)T_), pi = erT * sinf(ai * (float)T_);
#pragma unroll
        for (int k = 0; k < 7; ++k) {
            wTpow[k][c] = make_float2(pr, pi);
            float nr = pr * pr - pi * pi;
            pi = 2.f * pr * pi; pr = nr;
        }
    }
    __syncthreads();

    const float2* xb = (const float2*)x + (size_t)b * L_ + c * T_;
    const float ew0 = enc_w[h], ew1 = enc_w[H_ + h], eb = enc_b[h];

    // ---- Phase 1: E[c] via w^2 double-steps, zero-init, n tiled by 4 ----
    float zr[N_], zi[N_];
#pragma unroll
    for (int n = 0; n < N_; ++n) { zr[n] = 0.f; zi[n] = 0.f; }

#pragma unroll 1
    for (int tt = 0; tt < T_ / 16; ++tt) {      // 4 tiles of 16 timesteps
        float u[16];
        const float4* xq = (const float4*)xb + tt * 8;
#pragma unroll
        for (int j = 0; j < 8; ++j) {
            float4 xv = xq[j];
            u[2 * j]     = fmaf(xv.x, ew0, fmaf(xv.y, ew1, eb));
            u[2 * j + 1] = fmaf(xv.z, ew0, fmaf(xv.w, ew1, eb));
        }
#pragma unroll
        for (int ng = 0; ng < 8; ++ng) {        // groups of 4 n
            float4 q[4];
#pragma unroll
            for (int m = 0; m < 4; ++m) q[m] = pw[ng * 4 + m];
#pragma unroll
            for (int m = 0; m < 4; ++m) {
                int n = ng * 4 + m;
                float ar_ = zr[n], ai_ = zi[n];
#pragma unroll
                for (int t2 = 0; t2 < 8; ++t2) {
                    float ua = u[2 * t2], ub = u[2 * t2 + 1];
                    float mr = fmaf(q[m].z, ua, ub);
                    float mi = q[m].w * ua;
                    float nr = fmaf(q[m].x, ar_, fmaf(-q[m].y, ai_, mr));
                    ai_ = fmaf(q[m].x, ai_, fmaf(q[m].y, ar_, mi));
                    ar_ = nr;
                }
                zr[n] = ar_; zi[n] = ai_;
            }
        }
    }

    // ---- Phase 2: scan over chunks ----
#pragma unroll
    for (int k = 0; k < 6; ++k) {
        int s = 1 << k;
        float mask = (lane >= s) ? 1.f : 0.f;
#pragma unroll
        for (int n = 0; n < N_; ++n) {
            float2 q = wTpow[k][n];
            float vr = __shfl_up(zr[n], s, 64);
            float vi = __shfl_up(zi[n], s, 64);
            float adr = fmaf(q.x, vr, -(q.y * vi));
            float adi = fmaf(q.x, vi, q.y * vr);
            zr[n] = fmaf(mask, adr, zr[n]);
            zi[n] = fmaf(mask, adi, zi[n]);
        }
    }
    if (wv == 0) {
#pragma unroll
        for (int n = 0; n < N_; ++n) Sx[n][lane] = make_float2(zr[n], zi[n]);
    }
    __syncthreads();
    if (wv == 1) {
#pragma unroll
        for (int n = 0; n < N_; ++n) {
            float2 q = wTpow[6][n];
            float2 v = Sx[n][lane];
            zr[n] = fmaf(q.x, v.x, fmaf(-q.y, v.y, zr[n]));
            zi[n] = fmaf(q.x, v.y, fmaf(q.y, v.x, zi[n]));
        }
    }
    // shift by one chunk: S_in[c] = I[c-1]
    {
        bool l0 = (lane == 0);
#pragma unroll
        for (int n = 0; n < N_; ++n) {
            float2 bv = Sx[n][63];
            float br = (wv == 1) ? bv.x : 0.f;
            float bi = (wv == 1) ? bv.y : 0.f;
            float tr = __shfl_up(zr[n], 1, 64);
            float ti = __shfl_up(zi[n], 1, 64);
            zr[n] = l0 ? br : tr;
            zi[n] = l0 ? bi : ti;
        }
    }

    // ---- Phase 3: replay with incoming state, n tiled by 4; store gy ----
    const float Dh = Dp[h];
    float* gyp = gy + (size_t)(b * H_ + h) * L_ + c;
#pragma unroll 1
    for (int t4 = 0; t4 < T_ / 4; ++t4) {
        float u[4], p[4];
        const float4* xq = (const float4*)xb + t4 * 2;
        {
            float4 xa = xq[0], xbv = xq[1];
            u[0] = fmaf(xa.x, ew0, fmaf(xa.y, ew1, eb));
            u[1] = fmaf(xa.z, ew0, fmaf(xa.w, ew1, eb));
            u[2] = fmaf(xbv.x, ew0, fmaf(xbv.y, ew1, eb));
            u[3] = fmaf(xbv.z, ew0, fmaf(xbv.w, ew1, eb));
        }
#pragma unroll
        for (int j = 0; j < 4; ++j) p[j] = 0.f;
#pragma unroll
        for (int ng = 0; ng < 8; ++ng) {
            float4 q[4];
#pragma unroll
            for (int m = 0; m < 4; ++m) q[m] = cw4[ng * 4 + m];
#pragma unroll
            for (int m = 0; m < 4; ++m) {
                int n = ng * 4 + m;
                float ar_ = zr[n], ai_ = zi[n];
#pragma unroll
                for (int j = 0; j < 4; ++j) {
                    float nr = fmaf(q[m].x, ar_, fmaf(-q[m].y, ai_, u[j]));
                    ai_ = fmaf(q[m].x, ai_, q[m].y * ar_);
                    ar_ = nr;
                    p[j] = fmaf(q[m].z, ar_, fmaf(-q[m].w, ai_, p[j]));
                }
                zr[n] = ar_; zi[n] = ai_;
            }
        }
#pragma unroll
        for (int j = 0; j < 4; ++j) {
            float y = fmaf(Dh, u[j], 2.f * p[j]);
            gyp[(size_t)(t4 * 4 + j) * C_] = gelu_tanh(y);
        }
    }
}

// ---------------------------------------------------------------------------
// k_mix: pointwise GLU mix + pooled decode. W read with wave-uniform
// addresses straight from global -> scalar loads (s_load), zero LDS traffic;
// gy read coalesced per-lane with 16 loads in flight.
// ---------------------------------------------------------------------------
__global__ __launch_bounds__(256) void k_mix(
    const float* __restrict__ Wt, const float* __restrict__ gy,
    const float* __restrict__ out_b, const float* __restrict__ dec_w,
    float* __restrict__ out)
{
    __shared__ float red[4];
    int blk = blockIdx.x;
    int b = blk >> 7, lt = blk & 127;
    int l0 = lt * 64;
    int tid = threadIdx.x;
    int wq = tid >> 6, lane = tid & 63;
    int g0 = __builtin_amdgcn_readfirstlane(wq * 32);   // wave-uniform

    float aa[32], ag[32];
#pragma unroll
    for (int j = 0; j < 32; ++j) { aa[j] = 0.f; ag[j] = 0.f; }

    const float* gb = gy + (size_t)b * H_ * L_ + l0 + lane;
#pragma unroll 1
    for (int hc = 0; hc < 8; ++hc) {            // 16 h per iteration
        float v[16];
#pragma unroll
        for (int j = 0; j < 16; ++j)
            v[j] = gb[(size_t)(hc * 16 + j) * L_];      // 16 loads in flight
#pragma unroll
        for (int j = 0; j < 16; ++j) {
            const float* wrow = Wt + (hc * 16 + j) * 256 + g0;
#pragma unroll
            for (int j4 = 0; j4 < 8; ++j4) {
                float4 wa = *(const float4*)(wrow + j4 * 4);        // s_load
                float4 wg = *(const float4*)(wrow + 128 + j4 * 4);  // s_load
                aa[j4 * 4 + 0] = fmaf(wa.x, v[j], aa[j4 * 4 + 0]);
                aa[j4 * 4 + 1] = fmaf(wa.y, v[j], aa[j4 * 4 + 1]);
                aa[j4 * 4 + 2] = fmaf(wa.z, v[j], aa[j4 * 4 + 2]);
                aa[j4 * 4 + 3] = fmaf(wa.w, v[j], aa[j4 * 4 + 3]);
                ag[j4 * 4 + 0] = fmaf(wg.x, v[j], ag[j4 * 4 + 0]);
                ag[j4 * 4 + 1] = fmaf(wg.y, v[j], ag[j4 * 4 + 1]);
                ag[j4 * 4 + 2] = fmaf(wg.z, v[j], ag[j4 * 4 + 2]);
                ag[j4 * 4 + 3] = fmaf(wg.w, v[j], ag[j4 * 4 + 3]);
            }
        }
    }
    float s = 0.f;
#pragma unroll
    for (int j = 0; j < 32; ++j) {
        int g = g0 + j;
        float za = aa[j] + out_b[g];
        float zg = ag[j] + out_b[128 + g];
        float sig = __fdividef(1.f, 1.f + __expf(-zg));
        s = fmaf(dec_w[g], za * sig, s);
    }
#pragma unroll
    for (int off = 32; off; off >>= 1) s += __shfl_down(s, off, 64);
    if (lane == 0) red[wq] = s;
    __syncthreads();
    if (tid == 0) {
        float tot = (red[0] + red[1] + red[2] + red[3]) * (1.0f / (float)L_);
        atomicAdd(out + b, tot);
    }
}

// ---------------------------------------------------------------------------
extern "C" void kernel_launch(void* const* d_in, const int* in_sizes, int n_in,
                              void* d_out, int out_size, void* d_ws, size_t ws_size,
                              hipStream_t stream)
{
    const float* x         = (const float*)d_in[0];
    const float* enc_w     = (const float*)d_in[1];
    const float* enc_b     = (const float*)d_in[2];
    const float* log_dt    = (const float*)d_in[3];
    const float* log_A_real= (const float*)d_in[4];
    const float* A_imag    = (const float*)d_in[5];
    const float* C_re      = (const float*)d_in[6];
    const float* C_im      = (const float*)d_in[7];
    const float* Dp        = (const float*)d_in[8];
    const float* out_w     = (const float*)d_in[9];
    const float* out_b     = (const float*)d_in[10];
    const float* dec_w     = (const float*)d_in[11];
    const float* dec_b     = (const float*)d_in[12];
    float* out = (float*)d_out;

    char* ws = (char*)d_ws;
    float* Wt = (float*)(ws);
    float* gy = (float*)(ws + 131072);

    k_setup<<<129, 256, 0, stream>>>(out_w, dec_b, out, Wt);
    k_s4d<<<B_ * H_, C_, 0, stream>>>(x, enc_w, enc_b, log_dt, log_A_real,
                                      A_imag, C_re, C_im, Dp, gy);
    k_mix<<<B_ * 128, 256, 0, stream>>>(Wt, gy, out_b, dec_w, out);
}